// Round 1
// baseline (386.592 us; speedup 1.0000x reference)
//
#include <hip/hip_runtime.h>
#include <cstdint>
#include <cstddef>

#define B_ 256
#define N_ 512
#define H_ 30
#define CAP 96

typedef unsigned short u16;

// ---------------- workspace layout (bytes). Requires ws_size >= ~63 MB ----------------
constexpr size_t O_COLIDX = 0;                                   // u16 [131072*96]
constexpr size_t O_ROWCNT = 25165824;                            // int [131072]
constexpr size_t O_DIS    = 25690112;                            // f32 [131072]
constexpr size_t O_DIAG   = 26214400;                            // f32 [131072]
constexpr size_t O_XA     = 26738688;                            // f32 [256*512*30]
constexpr size_t O_XB     = 42467328;                            // f32 [256*512*30]
constexpr size_t O_S      = 58195968;                            // f32 [256*512*8]
constexpr size_t O_XP     = 62390272;                            // f32 [256*8*30]
constexpr size_t O_AP     = 62636032;                            // f32 [256*8*8]

// ---------------- pass 1: read adj ONCE, build sparse structure ----------------
// one wave per row; computes rowsum (excl diag), compacts nonzero off-diag col indices,
// captures raw diagonal value (needed by s^T adj s in diffpool).
__global__ __launch_bounds__(256) void build_sparse(
    const float* __restrict__ adj, u16* __restrict__ colidx,
    int* __restrict__ rowcnt, float* __restrict__ dis, float* __restrict__ diagv)
{
    int row  = blockIdx.x * 4 + (threadIdx.x >> 6);
    int lane = threadIdx.x & 63;
    int i    = row & (N_ - 1);
    const float4* arow = (const float4*)(adj + (size_t)row * N_);
    float4 v0 = arow[lane];
    float4 v1 = arow[lane + 64];
    float vals[8] = {v0.x, v0.y, v0.z, v0.w, v1.x, v1.y, v1.z, v1.w};

    float sum = 0.f, dloc = 0.f;
    int cnt = 0;
    #pragma unroll
    for (int k = 0; k < 8; ++k) {
        int j = (k < 4) ? (lane * 4 + k) : (256 + lane * 4 + (k - 4));
        float v = vals[k];
        if (j == i) dloc = v;
        else { sum += v; if (v != 0.f) ++cnt; }
    }
    // wave-wide exclusive prefix of counts
    int pre = cnt;
    #pragma unroll
    for (int d = 1; d < 64; d <<= 1) { int y = __shfl_up(pre, d, 64); if (lane >= d) pre += y; }
    int excl  = pre - cnt;
    int total = __shfl(pre, 63, 64);
    #pragma unroll
    for (int d = 32; d > 0; d >>= 1) { sum += __shfl_xor(sum, d, 64); dloc += __shfl_xor(dloc, d, 64); }

    u16* cb = colidx + (size_t)row * CAP;
    int c2 = 0;
    #pragma unroll
    for (int k = 0; k < 8; ++k) {
        int j = (k < 4) ? (lane * 4 + k) : (256 + lane * 4 + (k - 4));
        float v = vals[k];
        if (j != i && v != 0.f) { int p = excl + c2; if (p < CAP) cb[p] = (u16)j; ++c2; }
    }
    if (lane == 0) {
        rowcnt[row] = total > CAP ? CAP : total;
        dis[row]    = rsqrtf(fmaxf(1.f, sum + 1.f));   // diag of a is forced to 1
        diagv[row]  = dloc;
    }
}

// ---------------- level-0 GCN layer (N=512), fused xW + sparse propagate ----------------
// one block (512 threads) per batch. xw' = dis_j * (x @ W) staged in LDS (stride 31),
// then thread t == row t accumulates 30 floats over its neighbor list.
template <int FIN, bool RELU>
__global__ __launch_bounds__(512) void gcn_l0(
    const float* __restrict__ xin, const float* __restrict__ W,
    const float* __restrict__ bias, const u16* __restrict__ colidx,
    const int* __restrict__ rowcnt, const float* __restrict__ dis,
    float* __restrict__ xout)
{
    __shared__ float lxw[N_ * 31];
    __shared__ float lB[H_];
    int b = blockIdx.x, t = threadIdx.x;
    if (t < H_) lB[t] = bias[t];
    const float* xb   = xin + (size_t)b * N_ * FIN;
    const float* disb = dis + (size_t)b * N_;

    for (int it = 0; it < 30; ++it) {
        int id = t + it * 512;           // 0..15359
        int j = id / 30, h = id - j * 30;
        float acc = 0.f;
        #pragma unroll
        for (int f = 0; f < FIN; ++f) acc += xb[j * FIN + f] * W[f * H_ + h];
        lxw[j * 31 + h] = disb[j] * acc;
    }
    __syncthreads();

    int i = t;
    const u16* cl = colidx + ((size_t)b * N_ + i) * CAP;
    int cnt = rowcnt[b * N_ + i];
    float acc[H_];
    #pragma unroll
    for (int h = 0; h < H_; ++h) acc[h] = lxw[i * 31 + h];   // self loop (a_ii = 1)
    for (int k = 0; k < cnt; ++k) {
        int j = cl[k];
        #pragma unroll
        for (int h = 0; h < H_; ++h) acc[h] += lxw[j * 31 + h];
    }
    float di = disb[i];
    float* orow = xout + ((size_t)b * N_ + i) * H_;
    #pragma unroll
    for (int h = 0; h < H_; ++h) {
        float r = di * acc[h] + lB[h];
        if (RELU) r = fmaxf(r, 0.f);
        orow[h] = r;
    }
}

// ---------------- pool 0 (512 -> 8): logits, two softmaxes, reductions ----------------
__global__ __launch_bounds__(256) void pool_logits(
    const float* __restrict__ x3, const float* __restrict__ pw,
    const float* __restrict__ pb, float* __restrict__ L)
{
    __shared__ float lpw[H_ * 8];
    __shared__ float lpb[8];
    int t = threadIdx.x;
    if (t < H_ * 8) lpw[t] = pw[t];
    if (t < 8)      lpb[t] = pb[t];
    __syncthreads();
    int idx = blockIdx.x * 256 + t;      // (b,n,c), c fastest
    int c = idx & 7, n = (idx >> 3) & (N_ - 1), b = idx >> 12;
    const float* xr = x3 + ((size_t)b * N_ + n) * H_;
    float acc = lpb[c];
    #pragma unroll
    for (int h = 0; h < H_; ++h) acc += xr[h] * lpw[h * 8 + c];
    L[idx] = acc;
}

// softmax over node dim (axis=1): one wave per (b,c)
__global__ __launch_bounds__(256) void softmax_nodes(float* __restrict__ L)
{
    int gid = blockIdx.x * 256 + threadIdx.x;
    int wid = gid >> 6, lane = gid & 63;
    int b = wid >> 3, c = wid & 7;
    float* base = L + (size_t)b * N_ * 8 + c;
    float v[8]; float mx = -1e30f;
    #pragma unroll
    for (int k = 0; k < 8; ++k) { v[k] = base[(k * 64 + lane) * 8]; mx = fmaxf(mx, v[k]); }
    #pragma unroll
    for (int d = 32; d > 0; d >>= 1) mx = fmaxf(mx, __shfl_xor(mx, d, 64));
    float sm = 0.f;
    #pragma unroll
    for (int k = 0; k < 8; ++k) { v[k] = __expf(v[k] - mx); sm += v[k]; }
    #pragma unroll
    for (int d = 32; d > 0; d >>= 1) sm += __shfl_xor(sm, d, 64);
    float inv = 1.f / sm;
    #pragma unroll
    for (int k = 0; k < 8; ++k) base[(k * 64 + lane) * 8] = v[k] * inv;
}

// softmax over cluster dim (axis=-1): one thread per (b,n)
__global__ __launch_bounds__(256) void softmax_clusters(float* __restrict__ L)
{
    int idx = blockIdx.x * 256 + threadIdx.x;
    float4* p = (float4*)(L + (size_t)idx * 8);
    float4 a = p[0], bq = p[1];
    float v[8] = {a.x, a.y, a.z, a.w, bq.x, bq.y, bq.z, bq.w};
    float mx = -1e30f;
    #pragma unroll
    for (int k = 0; k < 8; ++k) mx = fmaxf(mx, v[k]);
    float sm = 0.f;
    #pragma unroll
    for (int k = 0; k < 8; ++k) { v[k] = __expf(v[k] - mx); sm += v[k]; }
    float inv = 1.f / sm;
    p[0] = make_float4(v[0]*inv, v[1]*inv, v[2]*inv, v[3]*inv);
    p[1] = make_float4(v[4]*inv, v[5]*inv, v[6]*inv, v[7]*inv);
}

// xp = s^T x, ap = s^T adj s (raw adj via sparse + stored diag). one block per batch.
__global__ __launch_bounds__(256) void pool_reduce(
    const float* __restrict__ s, const float* __restrict__ x3,
    const u16* __restrict__ colidx, const int* __restrict__ rowcnt,
    const float* __restrict__ diagv, float* __restrict__ xp, float* __restrict__ ap)
{
    __shared__ float ls[N_ * 8];
    __shared__ float lt[N_ * 8];
    int b = blockIdx.x, t = threadIdx.x;
    const float* sb = s + (size_t)b * N_ * 8;
    for (int k = t; k < N_ * 8; k += 256) ls[k] = sb[k];
    __syncthreads();
    for (int it = 0; it < 16; ++it) {
        int id = t + it * 256;
        int n = id >> 3, d = id & 7;
        const u16* cl = colidx + ((size_t)b * N_ + n) * CAP;
        int cnt = rowcnt[b * N_ + n];
        float acc = diagv[b * N_ + n] * ls[n * 8 + d];
        for (int k = 0; k < cnt; ++k) acc += ls[cl[k] * 8 + d];
        lt[id] = acc;
    }
    __syncthreads();
    if (t < 64) {
        int c = t >> 3, d = t & 7;
        float acc = 0.f;
        for (int n = 0; n < N_; ++n) acc += ls[n * 8 + c] * lt[n * 8 + d];
        ap[(size_t)b * 64 + t] = acc;
    }
    if (t < 240) {
        int c = t / 30, f = t - c * 30;
        const float* xr = x3 + (size_t)b * N_ * H_;
        float acc = 0.f;
        for (int n = 0; n < N_; ++n) acc += ls[n * 8 + c] * xr[n * H_ + f];
        xp[(size_t)b * 240 + t] = acc;
    }
}

// ---------------- tail: levels n=8,4,2,1 entirely in LDS, one block per batch ----------------
__device__ void gcn_small(int n, int t, const float* X, float* XN, float* XW, float* DIS,
                          const float* A, const float* W, const float* Bias, bool relu)
{
    if (t < n) {
        float s = 1.f;
        for (int j = 0; j < n; ++j) if (j != t) s += A[t * 8 + j];
        DIS[t] = rsqrtf(fmaxf(1.f, s));
    }
    __syncthreads();
    if (t < n * 30) {
        int i = t / 30, h = t - i * 30;
        float acc = 0.f;
        #pragma unroll
        for (int f = 0; f < 30; ++f) acc += X[i * 30 + f] * W[f * 30 + h];
        XW[t] = acc * DIS[i];
    }
    __syncthreads();
    if (t < n * 30) {
        int i = t / 30, h = t - i * 30;
        float acc = XW[i * 30 + h];
        for (int j = 0; j < n; ++j) if (j != i) acc += A[i * 8 + j] * XW[j * 30 + h];
        float r = DIS[i] * acc + Bias[h];
        if (relu) r = fmaxf(r, 0.f);
        XN[t] = r;
    }
    __syncthreads();
}

__device__ void pool_small(int n, int c, int t, const float* X, const float* A,
                           const float* PW, const float* PB,
                           float* S, float* T, float* LG, float* XN, float* AN)
{
    if (t < n * c) {
        int i = t / c, k = t - i * c;
        float acc = PB[k];
        #pragma unroll
        for (int h = 0; h < 30; ++h) acc += X[i * 30 + h] * PW[h * c + k];
        LG[i * 8 + k] = acc;
    }
    __syncthreads();
    if (t < c) {                                  // softmax over node dim
        float mx = -1e30f;
        for (int i = 0; i < n; ++i) mx = fmaxf(mx, LG[i * 8 + t]);
        float sm = 0.f;
        for (int i = 0; i < n; ++i) { float e = __expf(LG[i * 8 + t] - mx); LG[i * 8 + t] = e; sm += e; }
        float inv = 1.f / sm;
        for (int i = 0; i < n; ++i) LG[i * 8 + t] *= inv;
    }
    __syncthreads();
    if (t < n) {                                  // softmax over cluster dim
        float mx = -1e30f;
        for (int k = 0; k < c; ++k) mx = fmaxf(mx, LG[t * 8 + k]);
        float sm = 0.f;
        for (int k = 0; k < c; ++k) { float e = __expf(LG[t * 8 + k] - mx); S[t * 8 + k] = e; sm += e; }
        float inv = 1.f / sm;
        for (int k = 0; k < c; ++k) S[t * 8 + k] *= inv;
    }
    __syncthreads();
    if (t < c * 30) {                             // xp = s^T x
        int k = t / 30, f = t - k * 30;
        float acc = 0.f;
        for (int i = 0; i < n; ++i) acc += S[i * 8 + k] * X[i * 30 + f];
        XN[t] = acc;
    }
    if (t < n * c) {                              // T = A s  (raw adj)
        int i = t / c, d = t - i * c;
        float acc = 0.f;
        for (int m = 0; m < n; ++m) acc += A[i * 8 + m] * S[m * 8 + d];
        T[i * 8 + d] = acc;
    }
    __syncthreads();
    if (t < c * c) {                              // ap = s^T T
        int k = t / c, d = t - k * c;
        float acc = 0.f;
        for (int i = 0; i < n; ++i) acc += S[i * 8 + k] * T[i * 8 + d];
        AN[k * 8 + d] = acc;
    }
    __syncthreads();
}

__global__ __launch_bounds__(256) void tail_kernel(
    const float* __restrict__ xp0, const float* __restrict__ ap0,
    const float* cw4, const float* cb4, const float* cw5, const float* cb5,
    const float* cw6, const float* cb6, const float* cw7, const float* cb7,
    const float* pw1, const float* pb1, const float* pw2, const float* pb2,
    const float* pw3, const float* pb3, const float* lw, const float* lb,
    float* __restrict__ out)
{
    __shared__ float bufX[240], bufY[240], XW[240], DIS[8];
    __shared__ float bufA[64], bufB[64], S[64], T[64], LG[64];
    int b = blockIdx.x, t = threadIdx.x;
    if (t < 240) bufX[t] = xp0[(size_t)b * 240 + t];
    if (t < 64)  bufA[t] = ap0[(size_t)b * 64 + t];
    __syncthreads();
    float *X = bufX, *XN = bufY, *A = bufA, *AN = bufB;

    gcn_small(8, t, X, XN, XW, DIS, A, cw4, cb4, true);   { float* tmp = X; X = XN; XN = tmp; }
    pool_small(8, 4, t, X, A, pw1, pb1, S, T, LG, XN, AN); { float* tmp = X; X = XN; XN = tmp; tmp = A; A = AN; AN = tmp; }
    gcn_small(4, t, X, XN, XW, DIS, A, cw5, cb5, true);   { float* tmp = X; X = XN; XN = tmp; }
    pool_small(4, 2, t, X, A, pw2, pb2, S, T, LG, XN, AN); { float* tmp = X; X = XN; XN = tmp; tmp = A; A = AN; AN = tmp; }
    gcn_small(2, t, X, XN, XW, DIS, A, cw6, cb6, true);   { float* tmp = X; X = XN; XN = tmp; }
    pool_small(2, 1, t, X, A, pw3, pb3, S, T, LG, XN, AN); { float* tmp = X; X = XN; XN = tmp; tmp = A; A = AN; AN = tmp; }
    gcn_small(1, t, X, XN, XW, DIS, A, cw7, cb7, true);   { float* tmp = X; X = XN; XN = tmp; }

    if (t < 2) {
        float acc = lb[t];
        #pragma unroll
        for (int h = 0; h < 30; ++h) acc += X[h] * lw[h * 2 + t];
        out[(size_t)b * 2 + t] = acc;
    }
}

// ---------------- launch ----------------
extern "C" void kernel_launch(void* const* d_in, const int* in_sizes, int n_in,
                              void* d_out, int out_size, void* d_ws, size_t ws_size,
                              hipStream_t stream)
{
    const float* x   = (const float*)d_in[0];
    const float* adj = (const float*)d_in[1];
    const float *cw[8], *cb[8], *pw[4], *pb[4];
    for (int i = 0; i < 8; ++i) { cw[i] = (const float*)d_in[4 + 2 * i]; cb[i] = (const float*)d_in[5 + 2 * i]; }
    for (int i = 0; i < 4; ++i) { pw[i] = (const float*)d_in[20 + 2 * i]; pb[i] = (const float*)d_in[21 + 2 * i]; }
    const float* lw = (const float*)d_in[28];
    const float* lb = (const float*)d_in[29];

    char* ws = (char*)d_ws;
    u16*   colidx = (u16*)(ws + O_COLIDX);
    int*   rowcnt = (int*)(ws + O_ROWCNT);
    float* dis0   = (float*)(ws + O_DIS);
    float* diag0  = (float*)(ws + O_DIAG);
    float* xa     = (float*)(ws + O_XA);
    float* xbuf   = (float*)(ws + O_XB);
    float* s0     = (float*)(ws + O_S);
    float* xp0    = (float*)(ws + O_XP);
    float* ap0    = (float*)(ws + O_AP);

    build_sparse<<<(B_ * N_) / 4, 256, 0, stream>>>(adj, colidx, rowcnt, dis0, diag0);
    gcn_l0<14, true ><<<B_, 512, 0, stream>>>(x,    cw[0], cb[0], colidx, rowcnt, dis0, xa);
    gcn_l0<30, true ><<<B_, 512, 0, stream>>>(xa,   cw[1], cb[1], colidx, rowcnt, dis0, xbuf);
    gcn_l0<30, true ><<<B_, 512, 0, stream>>>(xbuf, cw[2], cb[2], colidx, rowcnt, dis0, xa);
    gcn_l0<30, false><<<B_, 512, 0, stream>>>(xa,   cw[3], cb[3], colidx, rowcnt, dis0, xbuf);
    pool_logits     <<<(B_ * N_ * 8) / 256, 256, 0, stream>>>(xbuf, pw[0], pb[0], s0);
    softmax_nodes   <<<(B_ * 8 * 64) / 256, 256, 0, stream>>>(s0);
    softmax_clusters<<<(B_ * N_) / 256, 256, 0, stream>>>(s0);
    pool_reduce     <<<B_, 256, 0, stream>>>(s0, xbuf, colidx, rowcnt, diag0, xp0, ap0);
    tail_kernel     <<<B_, 256, 0, stream>>>(xp0, ap0,
        cw[4], cb[4], cw[5], cb[5], cw[6], cb[6], cw[7], cb[7],
        pw[1], pb[1], pw[2], pb[2], pw[3], pb[3], lw, lb, (float*)d_out);
}

// Round 2
// 179.260 us; speedup vs baseline: 2.1566x; 2.1566x over previous
//
#include <hip/hip_runtime.h>
#include <cstdint>
#include <cstddef>

#define B_ 256
#define N_ 512
#define H_ 30
#define CAP 96

typedef unsigned short u16;

// ---------------- workspace layout (bytes), ~27 MB ----------------
constexpr size_t O_COLIDX = 0;          // u16 [131072*96]
constexpr size_t O_ROWCNT = 25165824;   // int [131072]
constexpr size_t O_DIS    = 25690112;   // f32 [131072]
constexpr size_t O_DIAG   = 26214400;   // f32 [131072]
constexpr size_t O_XP     = 26738688;   // f32 [256*240]
constexpr size_t O_AP     = 26984448;   // f32 [256*64]

// ---------------- pass 1: read adj ONCE, build sparse structure ----------------
__global__ __launch_bounds__(256) void build_sparse(
    const float* __restrict__ adj, u16* __restrict__ colidx,
    int* __restrict__ rowcnt, float* __restrict__ dis, float* __restrict__ diagv)
{
    int row  = blockIdx.x * 4 + (threadIdx.x >> 6);
    int lane = threadIdx.x & 63;
    int i    = row & (N_ - 1);
    const float4* arow = (const float4*)(adj + (size_t)row * N_);
    float4 v0 = arow[lane];
    float4 v1 = arow[lane + 64];
    float vals[8] = {v0.x, v0.y, v0.z, v0.w, v1.x, v1.y, v1.z, v1.w};

    float sum = 0.f, dloc = 0.f;
    int cnt = 0;
    #pragma unroll
    for (int k = 0; k < 8; ++k) {
        int jc = (k < 4) ? (lane * 4 + k) : (256 + lane * 4 + (k - 4));
        float v = vals[k];
        if (jc == i) dloc = v;
        else { sum += v; if (v != 0.f) ++cnt; }
    }
    int pre = cnt;
    #pragma unroll
    for (int d = 1; d < 64; d <<= 1) { int y = __shfl_up(pre, d, 64); if (lane >= d) pre += y; }
    int excl  = pre - cnt;
    int total = __shfl(pre, 63, 64);
    #pragma unroll
    for (int d = 32; d > 0; d >>= 1) { sum += __shfl_xor(sum, d, 64); dloc += __shfl_xor(dloc, d, 64); }

    u16* cb = colidx + (size_t)row * CAP;
    int c2 = 0;
    #pragma unroll
    for (int k = 0; k < 8; ++k) {
        int jc = (k < 4) ? (lane * 4 + k) : (256 + lane * 4 + (k - 4));
        float v = vals[k];
        if (jc != i && v != 0.f) { int p = excl + c2; if (p < CAP) cb[p] = (u16)jc; ++c2; }
    }
    if (lane == 0) {
        rowcnt[row] = total > CAP ? CAP : total;
        dis[row]    = rsqrtf(fmaxf(1.f, sum + 1.f));
        diagv[row]  = dloc;
    }
}

// add swizzled row j2 of XB into po[32]
__device__ __forceinline__ void addrow(float* po, const float* XB, int j2) {
    int e = j2 & 7;
    #pragma unroll
    for (int d = 0; d < 8; ++d) {
        const float4 v = *(const float4*)&XB[j2 * 32 + 4 * (d ^ e)];
        po[4*d+0] += v.x; po[4*d+1] += v.y; po[4*d+2] += v.z; po[4*d+3] += v.w;
    }
}

// one GCN layer at n=512, per-batch block, x resident in LDS (swizzled stride 32)
template <int FIN, bool RELU>
__device__ __forceinline__ void gcn_layer(
    int j, float di, int cnt, const uint4* cp,
    float* XA, float* XB,
    const float* __restrict__ Wg, const float* __restrict__ bg,
    float* po)
{
    int e = j & 7;
    float xr[32];
    #pragma unroll
    for (int d = 0; d < 8; ++d) {
        if (4 * d < FIN) {
            const float4 v = *(const float4*)&XA[j * 32 + 4 * (d ^ e)];
            xr[4*d] = v.x; xr[4*d+1] = v.y; xr[4*d+2] = v.z; xr[4*d+3] = v.w;
        }
    }
    float acc[32];
    #pragma unroll
    for (int h = 0; h < 32; ++h) acc[h] = 0.f;
    #pragma unroll
    for (int f = 0; f < FIN; ++f) {
        float xv = xr[f];
        #pragma unroll
        for (int h = 0; h < 30; ++h) acc[h] = fmaf(xv, Wg[f * 30 + h], acc[h]);
    }
    #pragma unroll
    for (int h = 0; h < 30; ++h) acc[h] *= di;
    acc[30] = acc[31] = 0.f;
    #pragma unroll
    for (int d = 0; d < 8; ++d)
        *(float4*)&XB[j * 32 + 4 * (d ^ e)] =
            make_float4(acc[4*d], acc[4*d+1], acc[4*d+2], acc[4*d+3]);
    __syncthreads();

    #pragma unroll
    for (int h = 0; h < 32; ++h) po[h] = acc[h];   // self loop (a_ii = 1)
    int nch = (cnt + 7) >> 3;
    uint4 cc = cp[0];
    for (int ch = 0; ch < nch; ++ch) {
        uint4 cn = cp[(ch + 1 < 12) ? (ch + 1) : 11];   // prefetch next chunk
        int kb = ch * 8;
        if (kb + 0 < cnt) addrow(po, XB, (int)(cc.x & 0xffffu));
        if (kb + 1 < cnt) addrow(po, XB, (int)(cc.x >> 16));
        if (kb + 2 < cnt) addrow(po, XB, (int)(cc.y & 0xffffu));
        if (kb + 3 < cnt) addrow(po, XB, (int)(cc.y >> 16));
        if (kb + 4 < cnt) addrow(po, XB, (int)(cc.z & 0xffffu));
        if (kb + 5 < cnt) addrow(po, XB, (int)(cc.z >> 16));
        if (kb + 6 < cnt) addrow(po, XB, (int)(cc.w & 0xffffu));
        if (kb + 7 < cnt) addrow(po, XB, (int)(cc.w >> 16));
        cc = cn;
    }
    #pragma unroll
    for (int h = 0; h < 30; ++h) {
        float r = fmaf(di, po[h], bg[h]);
        if (RELU) r = fmaxf(r, 0.f);
        po[h] = r;
    }
    po[30] = po[31] = 0.f;
    #pragma unroll
    for (int d = 0; d < 8; ++d)
        *(float4*)&XA[j * 32 + 4 * (d ^ e)] =
            make_float4(po[4*d], po[4*d+1], po[4*d+2], po[4*d+3]);
    __syncthreads();
}

// ---------------- mega: 4 GCN layers + DiffPool0, one block per batch ----------------
__global__ __launch_bounds__(512) void mega_kernel(
    const float* __restrict__ x0,
    const float* __restrict__ W0, const float* __restrict__ Bs0,
    const float* __restrict__ W1, const float* __restrict__ Bs1,
    const float* __restrict__ W2, const float* __restrict__ Bs2,
    const float* __restrict__ W3, const float* __restrict__ Bs3,
    const float* __restrict__ pw, const float* __restrict__ pb,
    const u16* __restrict__ colidx, const int* __restrict__ rowcnt,
    const float* __restrict__ dis, const float* __restrict__ diagv,
    float* __restrict__ xp, float* __restrict__ ap)
{
    __shared__ __align__(16) float XA[N_ * 32];
    __shared__ __align__(16) float XB[N_ * 32];
    int b = blockIdx.x, t = threadIdx.x, j = t;

    // stage x0 [512][14] -> XA swizzled
    const float2* x2 = (const float2*)(x0 + (size_t)b * N_ * 14);
    for (int k = t; k < N_ * 7; k += 512) {
        float2 v = x2[k];
        int ee = 2 * k; int j2 = ee / 14; int f = ee - j2 * 14;
        int p = j2 * 32 + (f ^ ((j2 & 7) * 4));
        *(float2*)&XA[p] = v;     // f even -> (f^c)+1 == (f+1)^c
    }
    float di = dis[(size_t)b * N_ + j];
    int cnt  = rowcnt[(size_t)b * N_ + j];
    const uint4* cp = (const uint4*)(colidx + ((size_t)b * N_ + j) * CAP);
    __syncthreads();

    float po[32];
    gcn_layer<14, true >(j, di, cnt, cp, XA, XB, W0, Bs0, po);
    gcn_layer<30, true >(j, di, cnt, cp, XA, XB, W1, Bs1, po);
    gcn_layer<30, true >(j, di, cnt, cp, XA, XB, W2, Bs2, po);
    gcn_layer<30, false>(j, di, cnt, cp, XA, XB, W3, Bs3, po);
    // po = x3 row j (also in XA swizzled). XB reusable now.
    float* ls  = XB;                       // [512*9] logits/s
    float* ltp = XB + N_ * 9;              // [512*8] A·s
    float* red = XB + N_ * 9 + N_ * 8;     // [2048] partials (16B aligned)

    // logits
    {
        float lg[8];
        #pragma unroll
        for (int c = 0; c < 8; ++c) lg[c] = pb[c];
        #pragma unroll
        for (int h = 0; h < 30; ++h) {
            float xv = po[h];
            #pragma unroll
            for (int c = 0; c < 8; ++c) lg[c] = fmaf(xv, pw[h * 8 + c], lg[c]);
        }
        #pragma unroll
        for (int c = 0; c < 8; ++c) ls[j * 9 + c] = lg[c];
    }
    __syncthreads();
    // softmax over nodes (axis=1): wave w handles c=w
    {
        int c = t >> 6, lane = t & 63;
        float v[8]; float mx = -1e30f;
        #pragma unroll
        for (int k = 0; k < 8; ++k) { v[k] = ls[(k * 64 + lane) * 9 + c]; mx = fmaxf(mx, v[k]); }
        #pragma unroll
        for (int d = 32; d > 0; d >>= 1) mx = fmaxf(mx, __shfl_xor(mx, d, 64));
        float sm = 0.f;
        #pragma unroll
        for (int k = 0; k < 8; ++k) { v[k] = __expf(v[k] - mx); sm += v[k]; }
        #pragma unroll
        for (int d = 32; d > 0; d >>= 1) sm += __shfl_xor(sm, d, 64);
        float inv = 1.f / sm;
        #pragma unroll
        for (int k = 0; k < 8; ++k) ls[(k * 64 + lane) * 9 + c] = v[k] * inv;
    }
    __syncthreads();
    // softmax over clusters (axis=-1): thread per node
    {
        float v[8]; float mx = -1e30f;
        #pragma unroll
        for (int c = 0; c < 8; ++c) { v[c] = ls[j * 9 + c]; mx = fmaxf(mx, v[c]); }
        float sm = 0.f;
        #pragma unroll
        for (int c = 0; c < 8; ++c) { v[c] = __expf(v[c] - mx); sm += v[c]; }
        float inv = 1.f / sm;
        #pragma unroll
        for (int c = 0; c < 8; ++c) ls[j * 9 + c] = v[c] * inv;
    }
    __syncthreads();
    // lt[n][d] = (A_raw · s)[n][d] via sparse + stored diagonal
    {
        float a8[8];
        float dg = diagv[(size_t)b * N_ + j];
        #pragma unroll
        for (int d = 0; d < 8; ++d) a8[d] = dg * ls[j * 9 + d];
        int nch = (cnt + 7) >> 3;
        uint4 cc = cp[0];
        for (int ch = 0; ch < nch; ++ch) {
            uint4 cn = cp[(ch + 1 < 12) ? (ch + 1) : 11];
            int kb = ch * 8;
            unsigned wv[1];
            #define LTNBR(WORD, SH, OFS) \
                if (kb + OFS < cnt) { int j2 = (int)(((WORD) >> (SH)) & 0xffffu); \
                    _Pragma("unroll") for (int d = 0; d < 8; ++d) a8[d] += ls[j2 * 9 + d]; }
            LTNBR(cc.x, 0, 0) LTNBR(cc.x, 16, 1)
            LTNBR(cc.y, 0, 2) LTNBR(cc.y, 16, 3)
            LTNBR(cc.z, 0, 4) LTNBR(cc.z, 16, 5)
            LTNBR(cc.w, 0, 6) LTNBR(cc.w, 16, 7)
            #undef LTNBR
            cc = cn; (void)wv;
        }
        #pragma unroll
        for (int d = 0; d < 8; ++d) ltp[j * 8 + d] = a8[d];
    }
    __syncthreads();
    // xp partials: xp[c][f] = sum_n s[n][c] x3[n][f]; seg = n-range of 64
    {
        int seg = t >> 6, cd = t & 63, c = cd >> 3, dd = cd & 7;
        float4 a4 = make_float4(0.f, 0.f, 0.f, 0.f);
        for (int n = seg * 64; n < seg * 64 + 64; ++n) {
            float sv = ls[n * 9 + c];
            const float4 xv = *(const float4*)&XA[n * 32 + 4 * (dd ^ (n & 7))];
            a4.x = fmaf(sv, xv.x, a4.x); a4.y = fmaf(sv, xv.y, a4.y);
            a4.z = fmaf(sv, xv.z, a4.z); a4.w = fmaf(sv, xv.w, a4.w);
        }
        *(float4*)&red[t * 4] = a4;
    }
    __syncthreads();
    if (t < 240) {
        int c = t / 30, f = t - c * 30, dd = f >> 2, m = f & 3;
        float s1 = 0.f;
        #pragma unroll
        for (int seg = 0; seg < 8; ++seg) s1 += red[(seg * 64 + c * 8 + dd) * 4 + m];
        xp[(size_t)b * 240 + t] = s1;
    }
    __syncthreads();
    // ap partials: ap[c][d] = sum_n s[n][c] lt[n][d]
    {
        int seg = t >> 6, cd = t & 63, c = cd >> 3, d = cd & 7;
        float s1 = 0.f;
        for (int n = seg * 64; n < seg * 64 + 64; ++n)
            s1 = fmaf(ls[n * 9 + c], ltp[n * 8 + d], s1);
        red[t] = s1;
    }
    __syncthreads();
    if (t < 64) {
        float s1 = 0.f;
        #pragma unroll
        for (int k = 0; k < 8; ++k) s1 += red[k * 64 + t];
        ap[(size_t)b * 64 + t] = s1;
    }
}

// ---------------- tail: levels n=8,4,2,1 entirely in LDS, one block per batch ----------------
__device__ void gcn_small(int n, int t, const float* X, float* XN, float* XW, float* DIS,
                          const float* A, const float* W, const float* Bias, bool relu)
{
    if (t < n) {
        float s = 1.f;
        for (int jj = 0; jj < n; ++jj) if (jj != t) s += A[t * 8 + jj];
        DIS[t] = rsqrtf(fmaxf(1.f, s));
    }
    __syncthreads();
    if (t < n * 30) {
        int i = t / 30, h = t - i * 30;
        float acc = 0.f;
        #pragma unroll
        for (int f = 0; f < 30; ++f) acc += X[i * 30 + f] * W[f * 30 + h];
        XW[t] = acc * DIS[i];
    }
    __syncthreads();
    if (t < n * 30) {
        int i = t / 30, h = t - i * 30;
        float acc = XW[i * 30 + h];
        for (int jj = 0; jj < n; ++jj) if (jj != i) acc += A[i * 8 + jj] * XW[jj * 30 + h];
        float r = DIS[i] * acc + Bias[h];
        if (relu) r = fmaxf(r, 0.f);
        XN[t] = r;
    }
    __syncthreads();
}

__device__ void pool_small(int n, int c, int t, const float* X, const float* A,
                           const float* PW, const float* PB,
                           float* S, float* T, float* LG, float* XN, float* AN)
{
    if (t < n * c) {
        int i = t / c, k = t - i * c;
        float acc = PB[k];
        #pragma unroll
        for (int h = 0; h < 30; ++h) acc += X[i * 30 + h] * PW[h * c + k];
        LG[i * 8 + k] = acc;
    }
    __syncthreads();
    if (t < c) {
        float mx = -1e30f;
        for (int i = 0; i < n; ++i) mx = fmaxf(mx, LG[i * 8 + t]);
        float sm = 0.f;
        for (int i = 0; i < n; ++i) { float e = __expf(LG[i * 8 + t] - mx); LG[i * 8 + t] = e; sm += e; }
        float inv = 1.f / sm;
        for (int i = 0; i < n; ++i) LG[i * 8 + t] *= inv;
    }
    __syncthreads();
    if (t < n) {
        float mx = -1e30f;
        for (int k = 0; k < c; ++k) mx = fmaxf(mx, LG[t * 8 + k]);
        float sm = 0.f;
        for (int k = 0; k < c; ++k) { float e = __expf(LG[t * 8 + k] - mx); S[t * 8 + k] = e; sm += e; }
        float inv = 1.f / sm;
        for (int k = 0; k < c; ++k) S[t * 8 + k] *= inv;
    }
    __syncthreads();
    if (t < c * 30) {
        int k = t / 30, f = t - k * 30;
        float acc = 0.f;
        for (int i = 0; i < n; ++i) acc += S[i * 8 + k] * X[i * 30 + f];
        XN[t] = acc;
    }
    if (t < n * c) {
        int i = t / c, d = t - i * c;
        float acc = 0.f;
        for (int m = 0; m < n; ++m) acc += A[i * 8 + m] * S[m * 8 + d];
        T[i * 8 + d] = acc;
    }
    __syncthreads();
    if (t < c * c) {
        int k = t / c, d = t - k * c;
        float acc = 0.f;
        for (int i = 0; i < n; ++i) acc += S[i * 8 + k] * T[i * 8 + d];
        AN[k * 8 + d] = acc;
    }
    __syncthreads();
}

__global__ __launch_bounds__(256) void tail_kernel(
    const float* __restrict__ xp0, const float* __restrict__ ap0,
    const float* cw4, const float* cb4, const float* cw5, const float* cb5,
    const float* cw6, const float* cb6, const float* cw7, const float* cb7,
    const float* pw1, const float* pb1, const float* pw2, const float* pb2,
    const float* pw3, const float* pb3, const float* lw, const float* lb,
    float* __restrict__ out)
{
    __shared__ float bufX[240], bufY[240], XW[240], DIS[8];
    __shared__ float bufA[64], bufB[64], S[64], T[64], LG[64];
    int b = blockIdx.x, t = threadIdx.x;
    if (t < 240) bufX[t] = xp0[(size_t)b * 240 + t];
    if (t < 64)  bufA[t] = ap0[(size_t)b * 64 + t];
    __syncthreads();
    float *X = bufX, *XN = bufY, *A = bufA, *AN = bufB;

    gcn_small(8, t, X, XN, XW, DIS, A, cw4, cb4, true);   { float* tmp = X; X = XN; XN = tmp; }
    pool_small(8, 4, t, X, A, pw1, pb1, S, T, LG, XN, AN); { float* tmp = X; X = XN; XN = tmp; tmp = A; A = AN; AN = tmp; }
    gcn_small(4, t, X, XN, XW, DIS, A, cw5, cb5, true);   { float* tmp = X; X = XN; XN = tmp; }
    pool_small(4, 2, t, X, A, pw2, pb2, S, T, LG, XN, AN); { float* tmp = X; X = XN; XN = tmp; tmp = A; A = AN; AN = tmp; }
    gcn_small(2, t, X, XN, XW, DIS, A, cw6, cb6, true);   { float* tmp = X; X = XN; XN = tmp; }
    pool_small(2, 1, t, X, A, pw3, pb3, S, T, LG, XN, AN); { float* tmp = X; X = XN; XN = tmp; tmp = A; A = AN; AN = tmp; }
    gcn_small(1, t, X, XN, XW, DIS, A, cw7, cb7, true);   { float* tmp = X; X = XN; XN = tmp; }

    if (t < 2) {
        float acc = lb[t];
        #pragma unroll
        for (int h = 0; h < 30; ++h) acc += X[h] * lw[h * 2 + t];
        out[(size_t)b * 2 + t] = acc;
    }
}

// ---------------- launch ----------------
extern "C" void kernel_launch(void* const* d_in, const int* in_sizes, int n_in,
                              void* d_out, int out_size, void* d_ws, size_t ws_size,
                              hipStream_t stream)
{
    const float* x   = (const float*)d_in[0];
    const float* adj = (const float*)d_in[1];
    const float *cw[8], *cb[8], *pw[4], *pb[4];
    for (int i = 0; i < 8; ++i) { cw[i] = (const float*)d_in[4 + 2 * i]; cb[i] = (const float*)d_in[5 + 2 * i]; }
    for (int i = 0; i < 4; ++i) { pw[i] = (const float*)d_in[20 + 2 * i]; pb[i] = (const float*)d_in[21 + 2 * i]; }
    const float* lw = (const float*)d_in[28];
    const float* lb = (const float*)d_in[29];

    char* ws = (char*)d_ws;
    u16*   colidx = (u16*)(ws + O_COLIDX);
    int*   rowcnt = (int*)(ws + O_ROWCNT);
    float* dis0   = (float*)(ws + O_DIS);
    float* diag0  = (float*)(ws + O_DIAG);
    float* xp0    = (float*)(ws + O_XP);
    float* ap0    = (float*)(ws + O_AP);

    build_sparse<<<(B_ * N_) / 4, 256, 0, stream>>>(adj, colidx, rowcnt, dis0, diag0);
    mega_kernel <<<B_, 512, 0, stream>>>(x,
        cw[0], cb[0], cw[1], cb[1], cw[2], cb[2], cw[3], cb[3],
        pw[0], pb[0], colidx, rowcnt, dis0, diag0, xp0, ap0);
    tail_kernel <<<B_, 256, 0, stream>>>(xp0, ap0,
        cw[4], cb[4], cw[5], cb[5], cw[6], cb[6], cw[7], cb[7],
        pw[1], pb[1], pw[2], pb[2], pw[3], pb[3], lw, lb, (float*)d_out);
}